// Round 1
// baseline (379.556 us; speedup 1.0000x reference)
//
#include <hip/hip_runtime.h>
#include <hip/hip_bf16.h>
#include <stdint.h>

typedef float    f32x4  __attribute__((ext_vector_type(4)));
typedef __bf16   bf16x8 __attribute__((ext_vector_type(8)));
typedef uint16_t u16;

#define NHEADS 16
#define DKV    64
#define DMODEL 1024
#define BATCH  2
#define SEQ    2048
#define ROWS   4096   /* BATCH*SEQ */

__device__ __forceinline__ u16 f2bf(float f) {
  union { float f; uint32_t u; } v; v.f = f;
  uint32_t r = v.u + 0x7fffu + ((v.u >> 16) & 1u);
  return (u16)(r >> 16);
}

__device__ __forceinline__ void gload16(const void* g, void* l) {
  __builtin_amdgcn_global_load_lds(
      (const __attribute__((address_space(1))) uint32_t*)g,
      (__attribute__((address_space(3))) uint32_t*)l, 16, 0, 0);
}

__device__ __forceinline__ f32x4 mfma16(bf16x8 a, bf16x8 b, f32x4 c) {
  return __builtin_amdgcn_mfma_f32_16x16x32_bf16(a, b, c, 0, 0, 0);
}

// ---------------- K1: cast x fp32 -> bf16, 8 elems/thread ----------------
__global__ void cast_x_kernel(const float* __restrict__ x, u16* __restrict__ xb) {
  int i = blockIdx.x * 256 + threadIdx.x;           // i indexes groups of 8
  const float4* p = (const float4*)(x + (size_t)i * 8);
  float4 a = p[0], b = p[1];
  u16* o = xb + (size_t)i * 8;
  u16 tmp[8] = { f2bf(a.x), f2bf(a.y), f2bf(a.z), f2bf(a.w),
                 f2bf(b.x), f2bf(b.y), f2bf(b.z), f2bf(b.w) };
  *(uint4*)o = *(uint4*)tmp;
}

// ---- K2: transpose+cast weights. blocks 0..767: wq/wk/wv -> wt[3072][1024]
// ----     blocks 768..1023: wo[1024][1024] -> wot[1024][1024] (B^T layouts)
__global__ void wtrans_kernel(const float* __restrict__ wq, const float* __restrict__ wk,
                              const float* __restrict__ wv, const float* __restrict__ wo,
                              u16* __restrict__ wt, u16* __restrict__ wot) {
  __shared__ float t[64][65];
  int blk = blockIdx.x, tid = threadIdx.x;
  const float* src; u16* dst; int sld, dld;
  if (blk < 768) {
    int p = blk >> 8, rem = blk & 255;
    int h = rem >> 4, dt = rem & 15;
    const float* w = (p == 0) ? wq : (p == 1) ? wk : wv;
    src = w + ((size_t)h * 1024 + dt * 64) * 64;   sld = 64;   // [64 d][64 dk]
    dst = wt + ((size_t)(p * 1024 + h * 64)) * 1024 + dt * 64; dld = 1024;
  } else {
    int t2 = blk - 768, rt = t2 >> 4, ct = t2 & 15;
    src = wo + (size_t)(rt * 64) * 1024 + ct * 64;  sld = 1024;
    dst = wot + (size_t)(ct * 64) * 1024 + rt * 64; dld = 1024;
  }
#pragma unroll
  for (int i = 0; i < 16; i++) {
    int e = tid + i * 256, r = e >> 6, c = e & 63;
    t[r][c] = src[(size_t)r * sld + c];
  }
  __syncthreads();
#pragma unroll
  for (int i = 0; i < 16; i++) {
    int e = tid + i * 256, r = e >> 6, c = e & 63;
    dst[(size_t)r * dld + c] = f2bf(t[c][r]);   // dst[r][c] = src[c][r]
  }
}

// ---------------- K3/K6: 128x128 GEMM, A[M][K] * Bt[N][K]^T ----------------
// EPI 0: scatter into q/k/v [B,H,S,64] bf16 (q scaled by 0.125)
// EPI 1: out = acc + xres (fp32)
template<int EPI>
__global__ __launch_bounds__(256) void gemm_bt(
    const u16* __restrict__ A, const u16* __restrict__ Bt, int K, int ntn,
    u16* __restrict__ qout, u16* __restrict__ kout, u16* __restrict__ vout,
    const float* __restrict__ xres, float* __restrict__ fout) {
  __shared__ __align__(16) u16 As[128 * 32];
  __shared__ __align__(16) u16 Bs[128 * 32];
  int tid = threadIdx.x, l = tid & 63, w = tid >> 6;
  int bid = blockIdx.x;
  int m0 = (bid / ntn) * 128, n0 = (bid % ntn) * 128;
  int wm = (w >> 1) * 64, wn = (w & 1) * 64;
  int cg = l >> 4, cl = l & 15;
  int lrow = l >> 2, lcol = l & 3;       // staging: 16 rows x 4 chunks(16B) per wave-call

  f32x4 acc[4][4];
#pragma unroll
  for (int i = 0; i < 4; i++)
#pragma unroll
    for (int j = 0; j < 4; j++) acc[i][j] = (f32x4){0.f, 0.f, 0.f, 0.f};

  for (int k0 = 0; k0 < K; k0 += 32) {
    __syncthreads();
    const u16* ga = A  + (size_t)(m0 + w * 16 + lrow) * K + k0 + lcol * 8;
    const u16* gb = Bt + (size_t)(n0 + w * 16 + lrow) * K + k0 + lcol * 8;
    gload16(ga,            &As[(w * 16) * 32]);
    gload16(ga + 64 * (size_t)K, &As[(w * 16 + 64) * 32]);
    gload16(gb,            &Bs[(w * 16) * 32]);
    gload16(gb + 64 * (size_t)K, &Bs[(w * 16 + 64) * 32]);
    __syncthreads();

    bf16x8 af[4], bfr[4];
#pragma unroll
    for (int mi = 0; mi < 4; mi++)
      af[mi] = *(const bf16x8*)&As[(wm + mi * 16 + cl) * 32 + cg * 8];
#pragma unroll
    for (int ni = 0; ni < 4; ni++)
      bfr[ni] = *(const bf16x8*)&Bs[(wn + ni * 16 + cl) * 32 + cg * 8];
#pragma unroll
    for (int mi = 0; mi < 4; mi++)
#pragma unroll
      for (int ni = 0; ni < 4; ni++)
        acc[mi][ni] = mfma16(af[mi], bfr[ni], acc[mi][ni]);
  }

  // epilogue: C/D layout col = lane&15, row = (lane>>4)*4 + reg  [m89-verified]
#pragma unroll
  for (int mi = 0; mi < 4; mi++)
#pragma unroll
    for (int ni = 0; ni < 4; ni++) {
      int nbase = n0 + wn + ni * 16 + cl;
#pragma unroll
      for (int r = 0; r < 4; r++) {
        int m = m0 + wm + mi * 16 + cg * 4 + r;
        float v = acc[mi][ni][r];
        if (EPI == 0) {
          int p = nbase >> 10, hh = (nbase >> 6) & 15, dk = nbase & 63;
          int b = m >> 11, s = m & 2047;
          size_t o = ((size_t)((b * 16 + hh)) * 2048 + s) * 64 + dk;
          u16* dst = (p == 0) ? qout : (p == 1) ? kout : vout;
          dst[o] = f2bf((p == 0) ? v * 0.125f : v);
        } else {
          size_t o = (size_t)m * 1024 + nbase;
          fout[o] = v + xres[o];
        }
      }
    }
}

// ---------------- K4: V [bh][2048][64] -> Vt [bh][64][2048] ----------------
__global__ void vtrans_kernel(const u16* __restrict__ v, u16* __restrict__ vt) {
  __shared__ u16 t[64][68];
  int blk = blockIdx.x, tid = threadIdx.x;
  int bh = blk >> 5, st = blk & 31;
  const u16* src = v + ((size_t)bh * 2048 + st * 64) * 64;
  u16* dst = vt + ((size_t)bh * 64) * 2048 + st * 64;
#pragma unroll
  for (int i = 0; i < 16; i++) {
    int e = tid + i * 256, r = e >> 6, c = e & 63;
    t[r][c] = src[(size_t)r * 64 + c];
  }
  __syncthreads();
#pragma unroll
  for (int i = 0; i < 16; i++) {
    int e = tid + i * 256, r = e >> 6, c = e & 63;
    dst[(size_t)r * 2048 + c] = t[c][r];
  }
}

// ---------------- K5: flash attention, 4 waves x 16 q-rows, KV tile 64 -----
__global__ __launch_bounds__(256) void attn_kernel(
    const u16* __restrict__ q, const u16* __restrict__ k,
    const u16* __restrict__ vt, u16* __restrict__ z) {
  __shared__ __align__(16) u16 plds[4][16][72];
  int tid = threadIdx.x, l = tid & 63, w = tid >> 6;
  int blk = blockIdx.x;
  int bh = blk >> 5, qt = blk & 31;
  int b = bh >> 4, h = bh & 15;
  int q0 = qt * 64 + w * 16;
  int cg = l >> 4, cl = l & 15;

  const u16* qb = q  + ((size_t)bh * 2048 + q0) * 64;
  const u16* kb = k  + (size_t)bh * 2048 * 64;
  const u16* vb = vt + (size_t)bh * 64 * 2048;

  // Q fragments (A-layout): row = cl, k = kk*32 + cg*8 + j   (Q pre-scaled by 1/8)
  bf16x8 aq0 = *(const bf16x8*)&qb[(size_t)cl * 64 + cg * 8];
  bf16x8 aq1 = *(const bf16x8*)&qb[(size_t)cl * 64 + 32 + cg * 8];

  f32x4 oacc[4];
#pragma unroll
  for (int i = 0; i < 4; i++) oacc[i] = (f32x4){0.f, 0.f, 0.f, 0.f};
  float mrun[4] = {-3.0e38f, -3.0e38f, -3.0e38f, -3.0e38f};
  float lrun[4] = {0.f, 0.f, 0.f, 0.f};

  for (int kv0 = 0; kv0 < SEQ; kv0 += 64) {
    // --- scores: QK^T, D layout row=q_local=(cg*4+r), col=kv_local=ni*16+cl
    f32x4 sc[4];
#pragma unroll
    for (int ni = 0; ni < 4; ni++) {
      const u16* kr = kb + (size_t)(kv0 + ni * 16 + cl) * 64 + cg * 8;
      bf16x8 b0 = *(const bf16x8*)kr;
      bf16x8 b1 = *(const bf16x8*)(kr + 32);
      f32x4 t = (f32x4){0.f, 0.f, 0.f, 0.f};
      t = mfma16(aq0, b0, t);
      t = mfma16(aq1, b1, t);
      sc[ni] = t;
    }
    // --- online softmax (row = (cg, r); reduce over cl via xor 1/2/4/8)
    float fac[4];
#pragma unroll
    for (int r = 0; r < 4; r++) {
      float mx = fmaxf(fmaxf(sc[0][r], sc[1][r]), fmaxf(sc[2][r], sc[3][r]));
      mx = fmaxf(mx, __shfl_xor(mx, 1));
      mx = fmaxf(mx, __shfl_xor(mx, 2));
      mx = fmaxf(mx, __shfl_xor(mx, 4));
      mx = fmaxf(mx, __shfl_xor(mx, 8));
      float mnew = fmaxf(mrun[r], mx);
      fac[r] = __expf(mrun[r] - mnew);
      mrun[r] = mnew;
      float rs = 0.f;
#pragma unroll
      for (int ni = 0; ni < 4; ni++) {
        float p = __expf(sc[ni][r] - mnew);
        sc[ni][r] = p;
        rs += p;
      }
      rs += __shfl_xor(rs, 1);
      rs += __shfl_xor(rs, 2);
      rs += __shfl_xor(rs, 4);
      rs += __shfl_xor(rs, 8);
      lrun[r] = lrun[r] * fac[r] + rs;
    }
#pragma unroll
    for (int nd = 0; nd < 4; nd++)
#pragma unroll
      for (int r = 0; r < 4; r++) oacc[nd][r] *= fac[r];

    // --- P: D-layout -> LDS -> A-layout (wave-private buffer, no barrier)
#pragma unroll
    for (int ni = 0; ni < 4; ni++)
#pragma unroll
      for (int r = 0; r < 4; r++)
        plds[w][cg * 4 + r][ni * 16 + cl] = f2bf(sc[ni][r]);

    bf16x8 pa0 = *(const bf16x8*)&plds[w][cl][cg * 8];
    bf16x8 pa1 = *(const bf16x8*)&plds[w][cl][32 + cg * 8];

    // --- PV: B-frag from Vt rows (dk-major), contiguous in kv
#pragma unroll
    for (int nd = 0; nd < 4; nd++) {
      const u16* vr = vb + (size_t)(nd * 16 + cl) * 2048 + kv0 + cg * 8;
      bf16x8 v0 = *(const bf16x8*)vr;
      bf16x8 v1 = *(const bf16x8*)(vr + 32);
      oacc[nd] = mfma16(pa0, v0, oacc[nd]);
      oacc[nd] = mfma16(pa1, v1, oacc[nd]);
    }
  }

  // --- epilogue: z[b*2048+q0+qloc][h*64 + dk], bf16
  u16* zb = z + ((size_t)(b * 2048) + q0) * 1024 + h * 64;
#pragma unroll
  for (int r = 0; r < 4; r++) {
    float inv = 1.0f / lrun[r];
#pragma unroll
    for (int nd = 0; nd < 4; nd++)
      zb[(size_t)(cg * 4 + r) * 1024 + nd * 16 + cl] = f2bf(oacc[nd][r] * inv);
  }
}

// --------------------------------------------------------------------------
extern "C" void kernel_launch(void* const* d_in, const int* in_sizes, int n_in,
                              void* d_out, int out_size, void* d_ws, size_t ws_size,
                              hipStream_t stream) {
  const float* x  = (const float*)d_in[0];
  const float* wq = (const float*)d_in[1];
  const float* wk = (const float*)d_in[2];
  const float* wv = (const float*)d_in[3];
  const float* wo = (const float*)d_in[4];
  float* out = (float*)d_out;

  uint8_t* ws = (uint8_t*)d_ws;
  u16* xb  = (u16*)(ws);                       // 8 MiB  [4096][1024]
  u16* wt  = (u16*)(ws + (8ull  << 20));       // 6 MiB  [3072][1024]
  u16* wot = (u16*)(ws + (14ull << 20));       // 2 MiB  [1024][1024]
  u16* qb  = (u16*)(ws + (16ull << 20));       // 8 MiB  [B,H,S,64]
  u16* kb  = (u16*)(ws + (24ull << 20));       // 8 MiB
  u16* vb  = (u16*)(ws + (32ull << 20));       // 8 MiB
  u16* vt  = (u16*)(ws + (40ull << 20));       // 8 MiB  [B,H,64,S]
  u16* zb  = (u16*)(ws + (48ull << 20));       // 8 MiB  [4096][1024]
  if (ws_size < (56ull << 20)) return;         // need 56 MiB scratch

  cast_x_kernel<<<2048, 256, 0, stream>>>(x, xb);
  wtrans_kernel<<<1024, 256, 0, stream>>>(wq, wk, wv, wo, wt, wot);
  gemm_bt<0><<<768, 256, 0, stream>>>(xb, wt, 1024, 24, qb, kb, vb, nullptr, nullptr);
  vtrans_kernel<<<1024, 256, 0, stream>>>(vb, vt);
  attn_kernel<<<1024, 256, 0, stream>>>(qb, kb, vt, zb);
  gemm_bt<1><<<256, 256, 0, stream>>>(zb, wot, 1024, 8, nullptr, nullptr, nullptr, x, out);
}

// Round 2
// 376.364 us; speedup vs baseline: 1.0085x; 1.0085x over previous
//
#include <hip/hip_runtime.h>
#include <hip/hip_bf16.h>
#include <stdint.h>

typedef float    f32x4  __attribute__((ext_vector_type(4)));
typedef __bf16   bf16x8 __attribute__((ext_vector_type(8)));
typedef uint16_t u16;

#define NHEADS 16
#define DKV    64
#define DMODEL 1024
#define BATCH  2
#define SEQ    2048
#define ROWS   4096   /* BATCH*SEQ */

__device__ __forceinline__ u16 f2bf(float f) {
  union { float f; uint32_t u; } v; v.f = f;
  uint32_t r = v.u + 0x7fffu + ((v.u >> 16) & 1u);
  return (u16)(r >> 16);
}

__device__ __forceinline__ void gload16(const void* g, void* l) {
  __builtin_amdgcn_global_load_lds(
      (const __attribute__((address_space(1))) uint32_t*)g,
      (__attribute__((address_space(3))) uint32_t*)l, 16, 0, 0);
}

__device__ __forceinline__ f32x4 mfma16(bf16x8 a, bf16x8 b, f32x4 c) {
  return __builtin_amdgcn_mfma_f32_16x16x32_bf16(a, b, c, 0, 0, 0);
}

// ---------------- K1: cast x fp32 -> bf16, 8 elems/thread ----------------
__global__ void cast_x_kernel(const float* __restrict__ x, u16* __restrict__ xb) {
  int i = blockIdx.x * 256 + threadIdx.x;           // i indexes groups of 8
  const float4* p = (const float4*)(x + (size_t)i * 8);
  float4 a = p[0], b = p[1];
  u16* o = xb + (size_t)i * 8;
  u16 tmp[8] = { f2bf(a.x), f2bf(a.y), f2bf(a.z), f2bf(a.w),
                 f2bf(b.x), f2bf(b.y), f2bf(b.z), f2bf(b.w) };
  *(uint4*)o = *(uint4*)tmp;
}

// ---- K2: transpose+cast weights. blocks 0..767: wq/wk/wv -> wt[3072][1024]
// ----     blocks 768..1023: wo[1024][1024] -> wot[1024][1024] (B^T layouts)
__global__ void wtrans_kernel(const float* __restrict__ wq, const float* __restrict__ wk,
                              const float* __restrict__ wv, const float* __restrict__ wo,
                              u16* __restrict__ wt, u16* __restrict__ wot) {
  __shared__ float t[64][65];
  int blk = blockIdx.x, tid = threadIdx.x;
  const float* src; u16* dst; int sld, dld;
  if (blk < 768) {
    int p = blk >> 8, rem = blk & 255;
    int h = rem >> 4, dt = rem & 15;
    const float* w = (p == 0) ? wq : (p == 1) ? wk : wv;
    src = w + ((size_t)h * 1024 + dt * 64) * 64;   sld = 64;   // [64 d][64 dk]
    dst = wt + ((size_t)(p * 1024 + h * 64)) * 1024 + dt * 64; dld = 1024;
  } else {
    int t2 = blk - 768, rt = t2 >> 4, ct = t2 & 15;
    src = wo + (size_t)(rt * 64) * 1024 + ct * 64;  sld = 1024;
    dst = wot + (size_t)(ct * 64) * 1024 + rt * 64; dld = 1024;
  }
#pragma unroll
  for (int i = 0; i < 16; i++) {
    int e = tid + i * 256, r = e >> 6, c = e & 63;
    t[r][c] = src[(size_t)r * sld + c];
  }
  __syncthreads();
#pragma unroll
  for (int i = 0; i < 16; i++) {
    int e = tid + i * 256, r = e >> 6, c = e & 63;
    dst[(size_t)r * dld + c] = f2bf(t[c][r]);   // dst[r][c] = src[c][r]
  }
}

// ---------------- K3/K6: 128x128 GEMM, A[M][K] * Bt[N][K]^T ----------------
// EPI 0: scatter into q/k/v [B,H,S,64] bf16 (q scaled by 0.125)
// EPI 1: out = acc + xres (fp32)
template<int EPI>
__global__ __launch_bounds__(256) void gemm_bt(
    const u16* __restrict__ A, const u16* __restrict__ Bt, int K, int ntn,
    u16* __restrict__ qout, u16* __restrict__ kout, u16* __restrict__ vout,
    const float* __restrict__ xres, float* __restrict__ fout) {
  __shared__ __align__(16) u16 As[128 * 32];
  __shared__ __align__(16) u16 Bs[128 * 32];
  int tid = threadIdx.x, l = tid & 63, w = tid >> 6;
  int bid = blockIdx.x;
  int m0 = (bid / ntn) * 128, n0 = (bid % ntn) * 128;
  int wm = (w >> 1) * 64, wn = (w & 1) * 64;
  int cg = l >> 4, cl = l & 15;
  int lrow = l >> 2, lcol = l & 3;       // staging: 16 rows x 4 chunks(16B) per wave-call

  f32x4 acc[4][4];
#pragma unroll
  for (int i = 0; i < 4; i++)
#pragma unroll
    for (int j = 0; j < 4; j++) acc[i][j] = (f32x4){0.f, 0.f, 0.f, 0.f};

  for (int k0 = 0; k0 < K; k0 += 32) {
    __syncthreads();
    const u16* ga = A  + (size_t)(m0 + w * 16 + lrow) * K + k0 + lcol * 8;
    const u16* gb = Bt + (size_t)(n0 + w * 16 + lrow) * K + k0 + lcol * 8;
    gload16(ga,            &As[(w * 16) * 32]);
    gload16(ga + 64 * (size_t)K, &As[(w * 16 + 64) * 32]);
    gload16(gb,            &Bs[(w * 16) * 32]);
    gload16(gb + 64 * (size_t)K, &Bs[(w * 16 + 64) * 32]);
    __syncthreads();

    bf16x8 af[4], bfr[4];
#pragma unroll
    for (int mi = 0; mi < 4; mi++)
      af[mi] = *(const bf16x8*)&As[(wm + mi * 16 + cl) * 32 + cg * 8];
#pragma unroll
    for (int ni = 0; ni < 4; ni++)
      bfr[ni] = *(const bf16x8*)&Bs[(wn + ni * 16 + cl) * 32 + cg * 8];
#pragma unroll
    for (int mi = 0; mi < 4; mi++)
#pragma unroll
      for (int ni = 0; ni < 4; ni++)
        acc[mi][ni] = mfma16(af[mi], bfr[ni], acc[mi][ni]);
  }

  // epilogue: C/D layout col = lane&15, row = (lane>>4)*4 + reg  [m89-verified]
#pragma unroll
  for (int mi = 0; mi < 4; mi++)
#pragma unroll
    for (int ni = 0; ni < 4; ni++) {
      int nbase = n0 + wn + ni * 16 + cl;
#pragma unroll
      for (int r = 0; r < 4; r++) {
        int m = m0 + wm + mi * 16 + cg * 4 + r;
        float v = acc[mi][ni][r];
        if (EPI == 0) {
          int p = nbase >> 10, hh = (nbase >> 6) & 15, dk = nbase & 63;
          int b = m >> 11, s = m & 2047;
          size_t o = ((size_t)((b * 16 + hh)) * 2048 + s) * 64 + dk;
          u16* dst = (p == 0) ? qout : (p == 1) ? kout : vout;
          dst[o] = f2bf((p == 0) ? v * 0.125f : v);
        } else {
          size_t o = (size_t)m * 1024 + nbase;
          fout[o] = v + xres[o];
        }
      }
    }
}

// ---------------- K4: V [bh][2048][64] -> Vt [bh][64][2048] ----------------
__global__ void vtrans_kernel(const u16* __restrict__ v, u16* __restrict__ vt) {
  __shared__ u16 t[64][68];
  int blk = blockIdx.x, tid = threadIdx.x;
  int bh = blk >> 5, st = blk & 31;
  const u16* src = v + ((size_t)bh * 2048 + st * 64) * 64;
  u16* dst = vt + ((size_t)bh * 64) * 2048 + st * 64;
#pragma unroll
  for (int i = 0; i < 16; i++) {
    int e = tid + i * 256, r = e >> 6, c = e & 63;
    t[r][c] = src[(size_t)r * 64 + c];
  }
  __syncthreads();
#pragma unroll
  for (int i = 0; i < 16; i++) {
    int e = tid + i * 256, r = e >> 6, c = e & 63;
    dst[(size_t)r * 2048 + c] = t[c][r];
  }
}

// ---------------- K5: flash attention, swapped-operand form ----------------
// Per wave: 16 q rows, KV tile 64. QK^T computed as mfma(K,Q) -> S[kv][q],
// col = q = lane&15: softmax reduce = 15 in-lane ops + 2 shfl (xor16/32).
// PV computed as mfma(Vt,P) -> Z[d][q], so rescale is one per-lane scalar mul.
__global__ __launch_bounds__(256) void attn_kernel(
    const u16* __restrict__ q, const u16* __restrict__ k,
    const u16* __restrict__ vt, u16* __restrict__ z) {
  __shared__ __align__(16) u16 plds[4][16][72];   // [wave][q][kv+pad], pitch 144B
  int tid = threadIdx.x, l = tid & 63, w = tid >> 6;
  int blk = blockIdx.x;
  int bh = blk >> 5, qt = blk & 31;
  int b = bh >> 4, h = bh & 15;
  int q0 = qt * 64 + w * 16;
  int cg = l >> 4, cl = l & 15;

  const u16* qb = q  + ((size_t)bh * 2048 + q0) * 64;
  const u16* kb = k  + (size_t)bh * 2048 * 64;
  const u16* vb = vt + (size_t)bh * 64 * 2048;

  // Q as B-fragment: col = q = cl, k = cg*8+j  (Q pre-scaled by 1/8 upstream)
  bf16x8 bq0 = *(const bf16x8*)&qb[(size_t)cl * 64 + cg * 8];
  bf16x8 bq1 = *(const bf16x8*)&qb[(size_t)cl * 64 + 32 + cg * 8];

  f32x4 oacc[4];    // oacc[nd][r] = Z[d = nd*16 + cg*4 + r][q = cl]
#pragma unroll
  for (int i = 0; i < 4; i++) oacc[i] = (f32x4){0.f, 0.f, 0.f, 0.f};
  float mrun = -3.0e38f, lrun = 0.f;   // per-lane scalars (q = cl)

  for (int kv0 = 0; kv0 < SEQ; kv0 += 64) {
    // --- V fragments: independent of scores; issue loads early to hide latency
    bf16x8 vf0[4], vf1[4];
#pragma unroll
    for (int nd = 0; nd < 4; nd++) {
      const u16* vr = vb + (size_t)(nd * 16 + cl) * 2048 + kv0 + cg * 8;
      vf0[nd] = *(const bf16x8*)vr;
      vf1[nd] = *(const bf16x8*)(vr + 32);
    }

    // --- scores swapped: sc[g][r] = S[kv = g*16 + cg*4 + r][q = cl]
    f32x4 sc[4];
#pragma unroll
    for (int g = 0; g < 4; g++) {
      const u16* kr = kb + (size_t)(kv0 + g * 16 + cl) * 64 + cg * 8;
      bf16x8 a0 = *(const bf16x8*)kr;
      bf16x8 a1 = *(const bf16x8*)(kr + 32);
      f32x4 t = (f32x4){0.f, 0.f, 0.f, 0.f};
      t = mfma16(a0, bq0, t);
      t = mfma16(a1, bq1, t);
      sc[g] = t;
    }

    // --- online softmax over kv (in-lane 16 + xor16/32), all per-lane scalar
    float m01 = fmaxf(fmaxf(sc[0][0], sc[0][1]), fmaxf(sc[0][2], sc[0][3]));
    float m23 = fmaxf(fmaxf(sc[1][0], sc[1][1]), fmaxf(sc[1][2], sc[1][3]));
    float m45 = fmaxf(fmaxf(sc[2][0], sc[2][1]), fmaxf(sc[2][2], sc[2][3]));
    float m67 = fmaxf(fmaxf(sc[3][0], sc[3][1]), fmaxf(sc[3][2], sc[3][3]));
    float mx = fmaxf(fmaxf(m01, m23), fmaxf(m45, m67));
    mx = fmaxf(mx, __shfl_xor(mx, 16));
    mx = fmaxf(mx, __shfl_xor(mx, 32));
    float mnew = fmaxf(mrun, mx);
    float fac = __expf(mrun - mnew);
    mrun = mnew;
    float rs = 0.f;
#pragma unroll
    for (int g = 0; g < 4; g++)
#pragma unroll
      for (int r = 0; r < 4; r++) {
        float p = __expf(sc[g][r] - mnew);
        sc[g][r] = p;
        rs += p;
      }
    rs += __shfl_xor(rs, 16);
    rs += __shfl_xor(rs, 32);
    lrun = lrun * fac + rs;
#pragma unroll
    for (int nd = 0; nd < 4; nd++)
#pragma unroll
      for (int r = 0; r < 4; r++) oacc[nd][r] *= fac;

    // --- P -> LDS as [q][kv]: 4 packed 8B writes per lane (wave-private)
#pragma unroll
    for (int g = 0; g < 4; g++) {
      uint32_t lo = (uint32_t)f2bf(sc[g][0]) | ((uint32_t)f2bf(sc[g][1]) << 16);
      uint32_t hi = (uint32_t)f2bf(sc[g][2]) | ((uint32_t)f2bf(sc[g][3]) << 16);
      *(uint2*)&plds[w][cl][g * 16 + cg * 4] = make_uint2(lo, hi);
    }
    // --- P as B-fragment: col = q = cl, k = kv = cg*8+j (+32)
    bf16x8 pb0 = *(const bf16x8*)&plds[w][cl][cg * 8];
    bf16x8 pb1 = *(const bf16x8*)&plds[w][cl][32 + cg * 8];

    // --- PV swapped: oacc[nd] += Vt-rows x P
#pragma unroll
    for (int nd = 0; nd < 4; nd++) {
      oacc[nd] = mfma16(vf0[nd], pb0, oacc[nd]);
      oacc[nd] = mfma16(vf1[nd], pb1, oacc[nd]);
    }
  }

  // --- epilogue: z[b*2048 + q0 + cl][h*64 + nd*16 + cg*4 + r], packed 8B stores
  float inv = 1.0f / lrun;
  u16* zb = z + ((size_t)(b * 2048) + q0) * 1024 + h * 64;
#pragma unroll
  for (int nd = 0; nd < 4; nd++) {
    uint32_t lo = (uint32_t)f2bf(oacc[nd][0] * inv) | ((uint32_t)f2bf(oacc[nd][1] * inv) << 16);
    uint32_t hi = (uint32_t)f2bf(oacc[nd][2] * inv) | ((uint32_t)f2bf(oacc[nd][3] * inv) << 16);
    *(uint2*)&zb[(size_t)cl * 1024 + nd * 16 + cg * 4] = make_uint2(lo, hi);
  }
}

// --------------------------------------------------------------------------
extern "C" void kernel_launch(void* const* d_in, const int* in_sizes, int n_in,
                              void* d_out, int out_size, void* d_ws, size_t ws_size,
                              hipStream_t stream) {
  const float* x  = (const float*)d_in[0];
  const float* wq = (const float*)d_in[1];
  const float* wk = (const float*)d_in[2];
  const float* wv = (const float*)d_in[3];
  const float* wo = (const float*)d_in[4];
  float* out = (float*)d_out;

  uint8_t* ws = (uint8_t*)d_ws;
  u16* xb  = (u16*)(ws);                       // 8 MiB  [4096][1024]
  u16* wt  = (u16*)(ws + (8ull  << 20));       // 6 MiB  [3072][1024]
  u16* wot = (u16*)(ws + (14ull << 20));       // 2 MiB  [1024][1024]
  u16* qb  = (u16*)(ws + (16ull << 20));       // 8 MiB  [B,H,S,64]
  u16* kb  = (u16*)(ws + (24ull << 20));       // 8 MiB
  u16* vb  = (u16*)(ws + (32ull << 20));       // 8 MiB
  u16* vt  = (u16*)(ws + (40ull << 20));       // 8 MiB  [B,H,64,S]
  u16* zb  = (u16*)(ws + (48ull << 20));       // 8 MiB  [4096][1024]
  if (ws_size < (56ull << 20)) return;         // need 56 MiB scratch

  cast_x_kernel<<<2048, 256, 0, stream>>>(x, xb);
  wtrans_kernel<<<1024, 256, 0, stream>>>(wq, wk, wv, wo, wt, wot);
  gemm_bt<0><<<768, 256, 0, stream>>>(xb, wt, 1024, 24, qb, kb, vb, nullptr, nullptr);
  vtrans_kernel<<<1024, 256, 0, stream>>>(vb, vt);
  attn_kernel<<<1024, 256, 0, stream>>>(qb, kb, vt, zb);
  gemm_bt<1><<<256, 256, 0, stream>>>(zb, wot, 1024, 8, nullptr, nullptr, nullptr, x, out);
}

// Round 4
// 212.140 us; speedup vs baseline: 1.7892x; 1.7741x over previous
//
#include <hip/hip_runtime.h>
#include <hip/hip_bf16.h>
#include <stdint.h>

typedef float    f32x4  __attribute__((ext_vector_type(4)));
typedef __bf16   bf16x8 __attribute__((ext_vector_type(8)));
typedef uint16_t u16;

#define NHEADS 16
#define DKV    64
#define DMODEL 1024
#define BATCH  2
#define SEQ    2048
#define ROWS   4096   /* BATCH*SEQ */

#define EXP2F(x) __builtin_amdgcn_exp2f(x)

__device__ __forceinline__ u16 f2bf(float f) {
  union { float f; uint32_t u; } v; v.f = f;
  uint32_t r = v.u + 0x7fffu + ((v.u >> 16) & 1u);
  return (u16)(r >> 16);
}

__device__ __forceinline__ void gload16(const void* g, void* l) {
  __builtin_amdgcn_global_load_lds(
      (const __attribute__((address_space(1))) uint32_t*)g,
      (__attribute__((address_space(3))) uint32_t*)l, 16, 0, 0);
}

__device__ __forceinline__ f32x4 mfma16(bf16x8 a, bf16x8 b, f32x4 c) {
  return __builtin_amdgcn_mfma_f32_16x16x32_bf16(a, b, c, 0, 0, 0);
}

// ---------------- K1: cast x fp32 -> bf16, 8 elems/thread ----------------
__global__ void cast_x_kernel(const float* __restrict__ x, u16* __restrict__ xb) {
  int i = blockIdx.x * 256 + threadIdx.x;           // i indexes groups of 8
  const float4* p = (const float4*)(x + (size_t)i * 8);
  float4 a = p[0], b = p[1];
  u16* o = xb + (size_t)i * 8;
  u16 tmp[8] = { f2bf(a.x), f2bf(a.y), f2bf(a.z), f2bf(a.w),
                 f2bf(b.x), f2bf(b.y), f2bf(b.z), f2bf(b.w) };
  *(uint4*)o = *(uint4*)tmp;
}

// ---- K2: transpose+cast weights. blocks 0..767: wq/wk/wv -> wt[3072][1024]
// ----     blocks 768..1023: wo[1024][1024] -> wot[1024][1024] (B^T layouts)
__global__ void wtrans_kernel(const float* __restrict__ wq, const float* __restrict__ wk,
                              const float* __restrict__ wv, const float* __restrict__ wo,
                              u16* __restrict__ wt, u16* __restrict__ wot) {
  __shared__ float t[64][65];
  int blk = blockIdx.x, tid = threadIdx.x;
  const float* src; u16* dst; int sld, dld;
  if (blk < 768) {
    int p = blk >> 8, rem = blk & 255;
    int h = rem >> 4, dt = rem & 15;
    const float* w = (p == 0) ? wq : (p == 1) ? wk : wv;
    src = w + ((size_t)h * 1024 + dt * 64) * 64;   sld = 64;   // [64 d][64 dk]
    dst = wt + ((size_t)(p * 1024 + h * 64)) * 1024 + dt * 64; dld = 1024;
  } else {
    int t2 = blk - 768, rt = t2 >> 4, ct = t2 & 15;
    src = wo + (size_t)(rt * 64) * 1024 + ct * 64;  sld = 1024;
    dst = wot + (size_t)(ct * 64) * 1024 + rt * 64; dld = 1024;
  }
#pragma unroll
  for (int i = 0; i < 16; i++) {
    int e = tid + i * 256, r = e >> 6, c = e & 63;
    t[r][c] = src[(size_t)r * sld + c];
  }
  __syncthreads();
#pragma unroll
  for (int i = 0; i < 16; i++) {
    int e = tid + i * 256, r = e >> 6, c = e & 63;
    dst[(size_t)r * dld + c] = f2bf(t[c][r]);   // dst[r][c] = src[c][r]
  }
}

// ---------------- K3/K6: 128x128 GEMM, A[M][K] * Bt[N][K]^T ----------------
// EPI 0: scatter into q/k/v [B,H,S,64] bf16 (q scaled by 0.125*log2e)
// EPI 1: out = acc + xres (fp32)
template<int EPI>
__global__ __launch_bounds__(256) void gemm_bt(
    const u16* __restrict__ A, const u16* __restrict__ Bt, int K, int ntn,
    u16* __restrict__ qout, u16* __restrict__ kout, u16* __restrict__ vout,
    const float* __restrict__ xres, float* __restrict__ fout) {
  __shared__ __align__(16) u16 As[128 * 32];
  __shared__ __align__(16) u16 Bs[128 * 32];
  int tid = threadIdx.x, l = tid & 63, w = tid >> 6;
  int bid = blockIdx.x;
  int m0 = (bid / ntn) * 128, n0 = (bid % ntn) * 128;
  int wm = (w >> 1) * 64, wn = (w & 1) * 64;
  int cg = l >> 4, cl = l & 15;
  int lrow = l >> 2, lcol = l & 3;

  f32x4 acc[4][4];
#pragma unroll
  for (int i = 0; i < 4; i++)
#pragma unroll
    for (int j = 0; j < 4; j++) acc[i][j] = (f32x4){0.f, 0.f, 0.f, 0.f};

  for (int k0 = 0; k0 < K; k0 += 32) {
    __syncthreads();
    const u16* ga = A  + (size_t)(m0 + w * 16 + lrow) * K + k0 + lcol * 8;
    const u16* gb = Bt + (size_t)(n0 + w * 16 + lrow) * K + k0 + lcol * 8;
    gload16(ga,            &As[(w * 16) * 32]);
    gload16(ga + 64 * (size_t)K, &As[(w * 16 + 64) * 32]);
    gload16(gb,            &Bs[(w * 16) * 32]);
    gload16(gb + 64 * (size_t)K, &Bs[(w * 16 + 64) * 32]);
    __syncthreads();

    bf16x8 af[4], bfr[4];
#pragma unroll
    for (int mi = 0; mi < 4; mi++)
      af[mi] = *(const bf16x8*)&As[(wm + mi * 16 + cl) * 32 + cg * 8];
#pragma unroll
    for (int ni = 0; ni < 4; ni++)
      bfr[ni] = *(const bf16x8*)&Bs[(wn + ni * 16 + cl) * 32 + cg * 8];
#pragma unroll
    for (int mi = 0; mi < 4; mi++)
#pragma unroll
      for (int ni = 0; ni < 4; ni++)
        acc[mi][ni] = mfma16(af[mi], bfr[ni], acc[mi][ni]);
  }

  // epilogue: C/D layout col = lane&15, row = (lane>>4)*4 + reg  [m89-verified]
#pragma unroll
  for (int mi = 0; mi < 4; mi++)
#pragma unroll
    for (int ni = 0; ni < 4; ni++) {
      int nbase = n0 + wn + ni * 16 + cl;
#pragma unroll
      for (int r = 0; r < 4; r++) {
        int m = m0 + wm + mi * 16 + cg * 4 + r;
        float v = acc[mi][ni][r];
        if (EPI == 0) {
          int p = nbase >> 10, hh = (nbase >> 6) & 15, dk = nbase & 63;
          int b = m >> 11, s = m & 2047;
          size_t o = ((size_t)((b * 16 + hh)) * 2048 + s) * 64 + dk;
          u16* dst = (p == 0) ? qout : (p == 1) ? kout : vout;
          // fold 1/sqrt(64) * log2(e) into Q so softmax uses exp2
          dst[o] = f2bf((p == 0) ? v * 0.18033688f : v);
        } else {
          size_t o = (size_t)m * 1024 + nbase;
          fout[o] = v + xres[o];
        }
      }
    }
}

// ---------------- K4: V [bh][2048][64] -> Vt [bh][64][2048] ----------------
__global__ void vtrans_kernel(const u16* __restrict__ v, u16* __restrict__ vt) {
  __shared__ u16 t[64][68];
  int blk = blockIdx.x, tid = threadIdx.x;
  int bh = blk >> 5, st = blk & 31;
  const u16* src = v + ((size_t)bh * 2048 + st * 64) * 64;
  u16* dst = vt + ((size_t)bh * 64) * 2048 + st * 64;
#pragma unroll
  for (int i = 0; i < 16; i++) {
    int e = tid + i * 256, r = e >> 6, c = e & 63;
    t[r][c] = src[(size_t)r * 64 + c];
  }
  __syncthreads();
#pragma unroll
  for (int i = 0; i < 16; i++) {
    int e = tid + i * 256, r = e >> 6, c = e & 63;
    dst[(size_t)r * 2048 + c] = t[c][r];
  }
}

// ---------------- K5: flash attention, LDS-staged K/V, 8 waves ------------
// Block = 8 waves x 16 q rows = 128 q. Grid 512 = 8 XCD x (4 bh x 16 qt):
// bh = (blk&7) + 8*((blk>>3)>>4)  -> each XCD owns 4 heads (K/V 2MB, L2-fit).
// K and Vt tiles staged to LDS via global_load_lds (dbuf, 2-phase schedule);
// XOR-swizzle: linear LDS dest + pre-swizzled global source chunk, reads XOR
// back -> ds_read_b128 spreads 8 lanes/bank-window (minimum).
__global__ __launch_bounds__(512) void attn_kernel(
    const u16* __restrict__ q, const u16* __restrict__ k,
    const u16* __restrict__ vt, u16* __restrict__ z) {
  __shared__ __align__(16) u16 Ks[2][64 * 64];   // [kv][d] tiles, 8KB each
  __shared__ __align__(16) u16 Vs[2][64 * 64];   // [d][kv] tiles
  __shared__ __align__(16) u16 Ps[8][16 * 64];   // per-wave P [q][kv], 2KB
  int tid = threadIdx.x, l = tid & 63, w = tid >> 6;
  int blk = blockIdx.x;
  int xcd = blk & 7, slot = blk >> 3;
  int bh = xcd + 8 * (slot >> 4), qt = slot & 15;
  int b = bh >> 4, h = bh & 15;
  int q0 = qt * 128 + w * 16;
  int cg = l >> 4, cl = l & 15;
  int swz = (cl & 7) << 4;                       // read-side XOR (row&7 == cl&7)

  const u16* qb = q  + ((size_t)bh * 2048 + q0) * 64;
  const u16* kb = k  + (size_t)bh * 2048 * 64;
  const u16* vb = vt + (size_t)bh * 64 * 2048;

  // staging geometry: wave w fills rows w*8..w*8+7 (1KB = one gload16 call)
  int srow = w * 8 + (l >> 3);                   // tile row this lane feeds
  int scb  = (l & 7) ^ (l >> 3);                 // pre-swizzled 16B chunk idx

  // Q as B-fragment: col = q = cl, k = cg*8+j (Q pre-scaled upstream)
  bf16x8 bq0 = *(const bf16x8*)&qb[(size_t)cl * 64 + cg * 8];
  bf16x8 bq1 = *(const bf16x8*)&qb[(size_t)cl * 64 + 32 + cg * 8];

  f32x4 oacc[4];    // oacc[nd][r] = Z[d = nd*16 + cg*4 + r][q = cl]
#pragma unroll
  for (int i = 0; i < 4; i++) oacc[i] = (f32x4){0.f, 0.f, 0.f, 0.f};
  float mrun = -3.0e38f, lrun = 0.f;

  // prologue: stage tile 0
  gload16(kb + (size_t)srow * 64 + scb * 8,   &Ks[0][(w * 8) * 64]);
  gload16(vb + (size_t)srow * 2048 + scb * 8, &Vs[0][(w * 8) * 64]);
  __syncthreads();

  for (int t = 0; t < 32; t++) {
    int cur = t & 1, nxt = cur ^ 1;
    if (t + 1 < 32) {   // stage next tile (lands during compute; drained by barrier)
      gload16(kb + ((size_t)(t + 1) * 64 + srow) * 64 + scb * 8,  &Ks[nxt][(w * 8) * 64]);
      gload16(vb + (size_t)srow * 2048 + (t + 1) * 64 + scb * 8,  &Vs[nxt][(w * 8) * 64]);
    }

    // --- QK^T swapped: sc[g][r] = S[kv = g*16 + cg*4 + r][q = cl]
    f32x4 sc[4];
#pragma unroll
    for (int g = 0; g < 4; g++) {
      const char* kp = (const char*)&Ks[cur][(g * 16 + cl) * 64];
      bf16x8 a0 = *(const bf16x8*)(kp + ((cg * 16)      ^ swz));
      bf16x8 a1 = *(const bf16x8*)(kp + ((cg * 16 + 64) ^ swz));
      f32x4 t2 = (f32x4){0.f, 0.f, 0.f, 0.f};
      t2 = mfma16(a0, bq0, t2);
      t2 = mfma16(a1, bq1, t2);
      sc[g] = t2;
    }

    // --- online softmax over kv (scores are in log2 domain; exp2)
    float m01 = fmaxf(fmaxf(sc[0][0], sc[0][1]), fmaxf(sc[0][2], sc[0][3]));
    float m23 = fmaxf(fmaxf(sc[1][0], sc[1][1]), fmaxf(sc[1][2], sc[1][3]));
    float m45 = fmaxf(fmaxf(sc[2][0], sc[2][1]), fmaxf(sc[2][2], sc[2][3]));
    float m67 = fmaxf(fmaxf(sc[3][0], sc[3][1]), fmaxf(sc[3][2], sc[3][3]));
    float mx = fmaxf(fmaxf(m01, m23), fmaxf(m45, m67));
    mx = fmaxf(mx, __shfl_xor(mx, 16));
    mx = fmaxf(mx, __shfl_xor(mx, 32));
    float mnew = fmaxf(mrun, mx);
    float fac = EXP2F(mrun - mnew);
    mrun = mnew;
    float rs = 0.f;
#pragma unroll
    for (int g = 0; g < 4; g++)
#pragma unroll
      for (int r = 0; r < 4; r++) {
        float p = EXP2F(sc[g][r] - mnew);
        sc[g][r] = p;
        rs += p;
      }
    rs += __shfl_xor(rs, 16);
    rs += __shfl_xor(rs, 32);
    lrun = lrun * fac + rs;
#pragma unroll
    for (int nd = 0; nd < 4; nd++)
#pragma unroll
      for (int r = 0; r < 4; r++) oacc[nd][r] *= fac;

    // --- P -> LDS [q=cl][kv], XOR-swizzled rows, 4x 8B writes (wave-private)
    char* pw = (char*)&Ps[w][cl * 64];
#pragma unroll
    for (int g = 0; g < 4; g++) {
      uint32_t lo = (uint32_t)f2bf(sc[g][0]) | ((uint32_t)f2bf(sc[g][1]) << 16);
      uint32_t hi = (uint32_t)f2bf(sc[g][2]) | ((uint32_t)f2bf(sc[g][3]) << 16);
      *(uint2*)(pw + ((g * 32 + cg * 8) ^ swz)) = make_uint2(lo, hi);
    }
    bf16x8 pb0 = *(const bf16x8*)(pw + ((cg * 16)      ^ swz));
    bf16x8 pb1 = *(const bf16x8*)(pw + ((cg * 16 + 64) ^ swz));

    // --- PV swapped: oacc[nd] += Vt rows (d) x P
#pragma unroll
    for (int nd = 0; nd < 4; nd++) {
      const char* vp = (const char*)&Vs[cur][(nd * 16 + cl) * 64];
      bf16x8 v0 = *(const bf16x8*)(vp + ((cg * 16)      ^ swz));
      bf16x8 v1 = *(const bf16x8*)(vp + ((cg * 16 + 64) ^ swz));
      oacc[nd] = mfma16(v0, pb0, oacc[nd]);
      oacc[nd] = mfma16(v1, pb1, oacc[nd]);
    }

    __syncthreads();   // drains vmcnt(0): next tile staged; buf[cur] free
  }

  // --- epilogue: z[b*2048 + q0 + cl][h*64 + nd*16 + cg*4 + r]
  float inv = 1.0f / lrun;
  u16* zb = z + ((size_t)(b * 2048) + q0) * 1024 + h * 64;
#pragma unroll
  for (int nd = 0; nd < 4; nd++) {
    uint32_t lo = (uint32_t)f2bf(oacc[nd][0] * inv) | ((uint32_t)f2bf(oacc[nd][1] * inv) << 16);
    uint32_t hi = (uint32_t)f2bf(oacc[nd][2] * inv) | ((uint32_t)f2bf(oacc[nd][3] * inv) << 16);
    *(uint2*)&zb[(size_t)cl * 1024 + nd * 16 + cg * 4] = make_uint2(lo, hi);
  }
}

// --------------------------------------------------------------------------
extern "C" void kernel_launch(void* const* d_in, const int* in_sizes, int n_in,
                              void* d_out, int out_size, void* d_ws, size_t ws_size,
                              hipStream_t stream) {
  const float* x  = (const float*)d_in[0];
  const float* wq = (const float*)d_in[1];
  const float* wk = (const float*)d_in[2];
  const float* wv = (const float*)d_in[3];
  const float* wo = (const float*)d_in[4];
  float* out = (float*)d_out;

  uint8_t* ws = (uint8_t*)d_ws;
  u16* xb  = (u16*)(ws);                       // 8 MiB  [4096][1024]
  u16* wt  = (u16*)(ws + (8ull  << 20));       // 6 MiB  [3072][1024]
  u16* wot = (u16*)(ws + (14ull << 20));       // 2 MiB  [1024][1024]
  u16* qb  = (u16*)(ws + (16ull << 20));       // 8 MiB  [B,H,S,64]
  u16* kb  = (u16*)(ws + (24ull << 20));       // 8 MiB
  u16* vb  = (u16*)(ws + (32ull << 20));       // 8 MiB
  u16* vt  = (u16*)(ws + (40ull << 20));       // 8 MiB  [B,H,64,S]
  u16* zb  = (u16*)(ws + (48ull << 20));       // 8 MiB  [4096][1024]
  if (ws_size < (56ull << 20)) return;         // need 56 MiB scratch

  cast_x_kernel<<<2048, 256, 0, stream>>>(x, xb);
  wtrans_kernel<<<1024, 256, 0, stream>>>(wq, wk, wv, wo, wt, wot);
  gemm_bt<0><<<768, 256, 0, stream>>>(xb, wt, 1024, 24, qb, kb, vb, nullptr, nullptr);
  vtrans_kernel<<<1024, 256, 0, stream>>>(vb, vt);
  attn_kernel<<<512, 512, 0, stream>>>(qb, kb, vt, zb);
  gemm_bt<1><<<256, 256, 0, stream>>>(zb, wot, 1024, 8, nullptr, nullptr, nullptr, x, out);
}

// Round 5
// 207.596 us; speedup vs baseline: 1.8283x; 1.0219x over previous
//
#include <hip/hip_runtime.h>
#include <hip/hip_bf16.h>
#include <stdint.h>

typedef float    f32x4  __attribute__((ext_vector_type(4)));
typedef __bf16   bf16x8 __attribute__((ext_vector_type(8)));
typedef __bf16   bf16x2 __attribute__((ext_vector_type(2)));
typedef uint16_t u16;

#define NHEADS 16
#define DKV    64
#define DMODEL 1024
#define BATCH  2
#define SEQ    2048
#define ROWS   4096   /* BATCH*SEQ */

#define EXP2F(x) __builtin_amdgcn_exp2f(x)

// native f32 -> bf16 (RTNE via HW v_cvt; compiler packs pairs to v_cvt_pk_bf16_f32)
__device__ __forceinline__ u16 f2bf(float f) {
  __bf16 h = (__bf16)f;
  union { __bf16 h; u16 u; } c; c.h = h; return c.u;
}
__device__ __forceinline__ uint32_t pk2(float a, float b) {
  union { bf16x2 v; uint32_t u; } c;
  c.v = (bf16x2){(__bf16)a, (__bf16)b};
  return c.u;
}

__device__ __forceinline__ void gload16(const void* g, void* l) {
  __builtin_amdgcn_global_load_lds(
      (const __attribute__((address_space(1))) uint32_t*)g,
      (__attribute__((address_space(3))) uint32_t*)l, 16, 0, 0);
}

__device__ __forceinline__ f32x4 mfma16(bf16x8 a, bf16x8 b, f32x4 c) {
  return __builtin_amdgcn_mfma_f32_16x16x32_bf16(a, b, c, 0, 0, 0);
}

// ------- K1: fused prep. blocks 0..2047: cast x fp32->bf16 (8 elem/thread)
// -------     blocks 2048..2815: wq/wk/wv -> wt[3072][1024] (B^T)
// -------     blocks 2816..3071: wo -> wot[1024][1024] (B^T)
__global__ void prep_kernel(const float* __restrict__ x, u16* __restrict__ xb,
                            const float* __restrict__ wq, const float* __restrict__ wk,
                            const float* __restrict__ wv, const float* __restrict__ wo,
                            u16* __restrict__ wt, u16* __restrict__ wot) {
  int blk = blockIdx.x, tid = threadIdx.x;
  if (blk < 2048) {
    int i = blk * 256 + tid;
    const float4* p = (const float4*)(x + (size_t)i * 8);
    float4 a = p[0], b = p[1];
    uint32_t o0 = pk2(a.x, a.y), o1 = pk2(a.z, a.w);
    uint32_t o2 = pk2(b.x, b.y), o3 = pk2(b.z, b.w);
    uint4 pk = make_uint4(o0, o1, o2, o3);
    *(uint4*)(xb + (size_t)i * 8) = pk;
    return;
  }
  __shared__ float t[64][65];
  int wblk = blk - 2048;
  const float* src; u16* dst; int sld, dld;
  if (wblk < 768) {
    int p = wblk >> 8, rem = wblk & 255;
    int h = rem >> 4, dt = rem & 15;
    const float* w = (p == 0) ? wq : (p == 1) ? wk : wv;
    src = w + ((size_t)h * 1024 + dt * 64) * 64;   sld = 64;   // [64 d][64 dk]
    dst = wt + ((size_t)(p * 1024 + h * 64)) * 1024 + dt * 64; dld = 1024;
  } else {
    int t2 = wblk - 768, rt = t2 >> 4, ct = t2 & 15;
    src = wo + (size_t)(rt * 64) * 1024 + ct * 64;  sld = 1024;
    dst = wot + (size_t)(ct * 64) * 1024 + rt * 64; dld = 1024;
  }
#pragma unroll
  for (int i = 0; i < 16; i++) {
    int e = tid + i * 256, r = e >> 6, c = e & 63;
    t[r][c] = src[(size_t)r * sld + c];
  }
  __syncthreads();
#pragma unroll
  for (int i = 0; i < 16; i++) {
    int e = tid + i * 256, r = e >> 6, c = e & 63;
    dst[(size_t)r * dld + c] = f2bf(t[c][r]);   // dst[r][c] = src[c][r]
  }
}

// ---------------- K2/K4: 128x128 GEMM, A[M][K] * Bt[N][K]^T ----------------
// EPI 0: scatter into q/k [B,H,S,64] bf16 (q scaled 0.125*log2e), V direct
//        to vt [B,H,64,S] (transposed)
// EPI 1: out = acc + xres (fp32)
template<int EPI>
__global__ __launch_bounds__(256) void gemm_bt(
    const u16* __restrict__ A, const u16* __restrict__ Bt, int K, int ntn,
    u16* __restrict__ qout, u16* __restrict__ kout, u16* __restrict__ vout,
    const float* __restrict__ xres, float* __restrict__ fout) {
  __shared__ __align__(16) u16 As[128 * 32];
  __shared__ __align__(16) u16 Bs[128 * 32];
  int tid = threadIdx.x, l = tid & 63, w = tid >> 6;
  // bijective XCD swizzle (grid % 8 == 0): consecutive work per XCD
  int nwg = gridDim.x, cpx = nwg >> 3;
  int bid = (blockIdx.x & 7) * cpx + (blockIdx.x >> 3);
  int m0 = (bid / ntn) * 128, n0 = (bid % ntn) * 128;
  int wm = (w >> 1) * 64, wn = (w & 1) * 64;
  int cg = l >> 4, cl = l & 15;
  int lrow = l >> 2, lcol = l & 3;

  f32x4 acc[4][4];
#pragma unroll
  for (int i = 0; i < 4; i++)
#pragma unroll
    for (int j = 0; j < 4; j++) acc[i][j] = (f32x4){0.f, 0.f, 0.f, 0.f};

  for (int k0 = 0; k0 < K; k0 += 32) {
    __syncthreads();
    const u16* ga = A  + (size_t)(m0 + w * 16 + lrow) * K + k0 + lcol * 8;
    const u16* gb = Bt + (size_t)(n0 + w * 16 + lrow) * K + k0 + lcol * 8;
    gload16(ga,            &As[(w * 16) * 32]);
    gload16(ga + 64 * (size_t)K, &As[(w * 16 + 64) * 32]);
    gload16(gb,            &Bs[(w * 16) * 32]);
    gload16(gb + 64 * (size_t)K, &Bs[(w * 16 + 64) * 32]);
    __syncthreads();

    bf16x8 af[4], bfr[4];
#pragma unroll
    for (int mi = 0; mi < 4; mi++)
      af[mi] = *(const bf16x8*)&As[(wm + mi * 16 + cl) * 32 + cg * 8];
#pragma unroll
    for (int ni = 0; ni < 4; ni++)
      bfr[ni] = *(const bf16x8*)&Bs[(wn + ni * 16 + cl) * 32 + cg * 8];
#pragma unroll
    for (int mi = 0; mi < 4; mi++)
#pragma unroll
      for (int ni = 0; ni < 4; ni++)
        acc[mi][ni] = mfma16(af[mi], bfr[ni], acc[mi][ni]);
  }

  // epilogue: C/D layout col = lane&15, row = (lane>>4)*4 + reg  [m89-verified]
#pragma unroll
  for (int mi = 0; mi < 4; mi++)
#pragma unroll
    for (int ni = 0; ni < 4; ni++) {
      int nbase = n0 + wn + ni * 16 + cl;
#pragma unroll
      for (int r = 0; r < 4; r++) {
        int m = m0 + wm + mi * 16 + cg * 4 + r;
        float v = acc[mi][ni][r];
        if (EPI == 0) {
          int p = nbase >> 10, hh = (nbase >> 6) & 15, dk = nbase & 63;
          int b = m >> 11, s = m & 2047;
          int bh = b * 16 + hh;
          if (p == 2) {
            // V directly transposed: vt[bh][dk][s]
            vout[((size_t)bh * 64 + dk) * 2048 + s] = f2bf(v);
          } else {
            size_t o = ((size_t)bh * 2048 + s) * 64 + dk;
            u16* dst = (p == 0) ? qout : kout;
            // fold 1/sqrt(64) * log2(e) into Q so softmax uses exp2
            dst[o] = f2bf((p == 0) ? v * 0.18033688f : v);
          }
        } else {
          size_t o = (size_t)m * 1024 + nbase;
          fout[o] = v + xres[o];
        }
      }
    }
}

// ---------------- K3: flash attention, LDS-staged K/V, 8 waves ------------
// Block = 8 waves x 16 q rows = 128 q. Grid 512 = 8 XCD x (4 bh x 16 qt):
// bh = (blk&7) + 8*((blk>>3)>>4)  -> each XCD owns 4 heads (K/V 2MB, L2-fit).
// K and Vt tiles staged to LDS via global_load_lds (dbuf, 2-phase schedule);
// XOR-swizzle: linear LDS dest + pre-swizzled global source chunk, reads XOR
// back. Softmax: swapped QK^T (col=q), defer-max (THR=8, log2 domain),
// native v_cvt bf16 packing, setprio around MFMA clusters.
__global__ __launch_bounds__(512) void attn_kernel(
    const u16* __restrict__ q, const u16* __restrict__ k,
    const u16* __restrict__ vt, u16* __restrict__ z) {
  __shared__ __align__(16) u16 Ks[2][64 * 64];   // [kv][d] tiles, 8KB each
  __shared__ __align__(16) u16 Vs[2][64 * 64];   // [d][kv] tiles
  __shared__ __align__(16) u16 Ps[8][16 * 64];   // per-wave P [q][kv], 2KB
  int tid = threadIdx.x, l = tid & 63, w = tid >> 6;
  int blk = blockIdx.x;
  int xcd = blk & 7, slot = blk >> 3;
  int bh = xcd + 8 * (slot >> 4), qt = slot & 15;
  int b = bh >> 4, h = bh & 15;
  int q0 = qt * 128 + w * 16;
  int cg = l >> 4, cl = l & 15;
  int swz = (cl & 7) << 4;                       // read-side XOR (row&7 == cl&7)

  const u16* qb = q  + ((size_t)bh * 2048 + q0) * 64;
  const u16* kb = k  + (size_t)bh * 2048 * 64;
  const u16* vb = vt + (size_t)bh * 64 * 2048;

  // staging geometry: wave w fills rows w*8..w*8+7 (1KB = one gload16 call)
  int srow = w * 8 + (l >> 3);                   // tile row this lane feeds
  int scb  = (l & 7) ^ (l >> 3);                 // pre-swizzled 16B chunk idx

  // Q as B-fragment: col = q = cl, k = cg*8+j (Q pre-scaled upstream)
  bf16x8 bq0 = *(const bf16x8*)&qb[(size_t)cl * 64 + cg * 8];
  bf16x8 bq1 = *(const bf16x8*)&qb[(size_t)cl * 64 + 32 + cg * 8];

  f32x4 oacc[4];    // oacc[nd][r] = Z[d = nd*16 + cg*4 + r][q = cl]
#pragma unroll
  for (int i = 0; i < 4; i++) oacc[i] = (f32x4){0.f, 0.f, 0.f, 0.f};
  float mrun = -3.0e38f, lrun = 0.f;

  // prologue: stage tile 0
  gload16(kb + (size_t)srow * 64 + scb * 8,   &Ks[0][(w * 8) * 64]);
  gload16(vb + (size_t)srow * 2048 + scb * 8, &Vs[0][(w * 8) * 64]);
  __syncthreads();

  for (int t = 0; t < 32; t++) {
    int cur = t & 1, nxt = cur ^ 1;
    if (t + 1 < 32) {   // stage next tile (lands during compute; drained by barrier)
      gload16(kb + ((size_t)(t + 1) * 64 + srow) * 64 + scb * 8,  &Ks[nxt][(w * 8) * 64]);
      gload16(vb + (size_t)srow * 2048 + (t + 1) * 64 + scb * 8,  &Vs[nxt][(w * 8) * 64]);
    }

    // --- QK^T swapped: sc[g][r] = S[kv = g*16 + cg*4 + r][q = cl]
    f32x4 sc[4];
    __builtin_amdgcn_s_setprio(1);
#pragma unroll
    for (int g = 0; g < 4; g++) {
      const char* kp = (const char*)&Ks[cur][(g * 16 + cl) * 64];
      bf16x8 a0 = *(const bf16x8*)(kp + ((cg * 16)      ^ swz));
      bf16x8 a1 = *(const bf16x8*)(kp + ((cg * 16 + 64) ^ swz));
      f32x4 t2 = (f32x4){0.f, 0.f, 0.f, 0.f};
      t2 = mfma16(a0, bq0, t2);
      t2 = mfma16(a1, bq1, t2);
      sc[g] = t2;
    }
    __builtin_amdgcn_s_setprio(0);

    // --- online softmax over kv (log2 domain, exp2), defer-max THR=8
    float m01 = fmaxf(fmaxf(sc[0][0], sc[0][1]), fmaxf(sc[0][2], sc[0][3]));
    float m23 = fmaxf(fmaxf(sc[1][0], sc[1][1]), fmaxf(sc[1][2], sc[1][3]));
    float m45 = fmaxf(fmaxf(sc[2][0], sc[2][1]), fmaxf(sc[2][2], sc[2][3]));
    float m67 = fmaxf(fmaxf(sc[3][0], sc[3][1]), fmaxf(sc[3][2], sc[3][3]));
    float mx = fmaxf(fmaxf(m01, m23), fmaxf(m45, m67));
    mx = fmaxf(mx, __shfl_xor(mx, 16));
    mx = fmaxf(mx, __shfl_xor(mx, 32));
    if (!__all(mx <= mrun + 8.0f)) {   // rescale only when max grew enough
      float mnew = fmaxf(mrun, mx);
      float fac = EXP2F(mrun - mnew);
      mrun = mnew;
      lrun *= fac;
#pragma unroll
      for (int nd = 0; nd < 4; nd++)
#pragma unroll
        for (int r = 0; r < 4; r++) oacc[nd][r] *= fac;
    }
    float rs = 0.f;
#pragma unroll
    for (int g = 0; g < 4; g++)
#pragma unroll
      for (int r = 0; r < 4; r++) {
        float p = EXP2F(sc[g][r] - mrun);   // bounded by 2^8 when deferred
        sc[g][r] = p;
        rs += p;
      }
    rs += __shfl_xor(rs, 16);
    rs += __shfl_xor(rs, 32);
    lrun += rs;

    // --- P -> LDS [q=cl][kv], XOR-swizzled rows, 4x 8B packed writes
    char* pw = (char*)&Ps[w][cl * 64];
#pragma unroll
    for (int g = 0; g < 4; g++) {
      uint32_t lo = pk2(sc[g][0], sc[g][1]);
      uint32_t hi = pk2(sc[g][2], sc[g][3]);
      *(uint2*)(pw + ((g * 32 + cg * 8) ^ swz)) = make_uint2(lo, hi);
    }
    bf16x8 pb0 = *(const bf16x8*)(pw + ((cg * 16)      ^ swz));
    bf16x8 pb1 = *(const bf16x8*)(pw + ((cg * 16 + 64) ^ swz));

    // --- PV swapped: oacc[nd] += Vt rows (d) x P
    __builtin_amdgcn_s_setprio(1);
#pragma unroll
    for (int nd = 0; nd < 4; nd++) {
      const char* vp = (const char*)&Vs[cur][(nd * 16 + cl) * 64];
      bf16x8 v0 = *(const bf16x8*)(vp + ((cg * 16)      ^ swz));
      bf16x8 v1 = *(const bf16x8*)(vp + ((cg * 16 + 64) ^ swz));
      oacc[nd] = mfma16(v0, pb0, oacc[nd]);
      oacc[nd] = mfma16(v1, pb1, oacc[nd]);
    }
    __builtin_amdgcn_s_setprio(0);

    __syncthreads();   // drains vmcnt(0): next tile staged; buf[cur] free
  }

  // --- epilogue: z[b*2048 + q0 + cl][h*64 + nd*16 + cg*4 + r]
  float inv = 1.0f / lrun;
  u16* zb = z + ((size_t)(b * 2048) + q0) * 1024 + h * 64;
#pragma unroll
  for (int nd = 0; nd < 4; nd++) {
    uint32_t lo = pk2(oacc[nd][0] * inv, oacc[nd][1] * inv);
    uint32_t hi = pk2(oacc[nd][2] * inv, oacc[nd][3] * inv);
    *(uint2*)&zb[(size_t)cl * 1024 + nd * 16 + cg * 4] = make_uint2(lo, hi);
  }
}

// --------------------------------------------------------------------------
extern "C" void kernel_launch(void* const* d_in, const int* in_sizes, int n_in,
                              void* d_out, int out_size, void* d_ws, size_t ws_size,
                              hipStream_t stream) {
  const float* x  = (const float*)d_in[0];
  const float* wq = (const float*)d_in[1];
  const float* wk = (const float*)d_in[2];
  const float* wv = (const float*)d_in[3];
  const float* wo = (const float*)d_in[4];
  float* out = (float*)d_out;

  uint8_t* ws = (uint8_t*)d_ws;
  u16* xb  = (u16*)(ws);                       // 8 MiB  [4096][1024]
  u16* wt  = (u16*)(ws + (8ull  << 20));       // 6 MiB  [3072][1024]
  u16* wot = (u16*)(ws + (14ull << 20));       // 2 MiB  [1024][1024]
  u16* qb  = (u16*)(ws + (16ull << 20));       // 8 MiB  [B,H,S,64]
  u16* kb  = (u16*)(ws + (24ull << 20));       // 8 MiB
  u16* vt  = (u16*)(ws + (32ull << 20));       // 8 MiB  [B,H,64,S]
  u16* zb  = (u16*)(ws + (40ull << 20));       // 8 MiB  [4096][1024]
  if (ws_size < (48ull << 20)) return;         // need 48 MiB scratch

  prep_kernel<<<3072, 256, 0, stream>>>(x, xb, wq, wk, wv, wo, wt, wot);
  gemm_bt<0><<<768, 256, 0, stream>>>(xb, wt, 1024, 24, qb, kb, vt, nullptr, nullptr);
  attn_kernel<<<512, 512, 0, stream>>>(qb, kb, vt, zb);
  gemm_bt<1><<<256, 256, 0, stream>>>(zb, wot, 1024, 8, nullptr, nullptr, nullptr, x, out);
}